// Round 1
// baseline (6870.828 us; speedup 1.0000x reference)
//
#include <hip/hip_runtime.h>

// Problem: B=16, C=256, L=2048, K=2048 codewords, D=256 codebook dim.
// flat[n][j] = z_e[b=j&15][c=(n&15)*16+(j>>4)][l=n>>4],  N=32768 rows.
// Outputs (f32, concatenated): quantized[8388608], indices[32768], loss[1].
// vq_loss = 1.25 * mean((quantized - flat)^2)   (stop_gradient is value-neutral)

#define ZE_CL   (256 * 2048)
#define NROWS   32768
#define KC      2048
#define DD      256
#define IDX_OFF 8388608
#define LOSS_OFF (8388608 + 32768)

// ---------------- kernel 0: codeword squared norms -> ws ----------------
__global__ void vq_enorm(const float* __restrict__ emb, float* __restrict__ enorm) {
    int k = blockIdx.x * blockDim.x + threadIdx.x;
    if (k >= KC) return;
    const float4* e4 = (const float4*)(emb + (size_t)k * DD);
    float s = 0.f;
#pragma unroll
    for (int i = 0; i < DD / 4; ++i) {
        float4 v = e4[i];
        s += v.x * v.x + v.y * v.y + v.z * v.z + v.w * v.w;
    }
    enorm[k] = s;
}

// ---------------- kernel 1: z_e -> flat A (materialized in d_out Q region) ----
// Block handles one (l-tile of 16, m) pair. LDS tile keeps global writes coalesced.
// T stored with jp = 17*c_lo + b (row stride 272) to break write-phase conflicts.
__global__ void vq_transpose(const float* __restrict__ ze, float* __restrict__ A) {
    __shared__ float T[16 * 272];
    int tid = threadIdx.x;
    int m  = blockIdx.x & 15;
    int lt = blockIdx.x >> 4;       // 0..127
    int l0 = lt * 16;
#pragma unroll
    for (int it = 0; it < 4; ++it) {
        int p   = tid + it * 256;   // 0..1023
        int b   = p >> 6;           // 0..15
        int clo = (p >> 2) & 15;    // 0..15
        int l4  = p & 3;            // 0..3
        const float* g = ze + (size_t)b * ZE_CL + (size_t)(m * 16 + clo) * 2048 + l0 + 4 * l4;
        float4 v = *(const float4*)g;
        int jp = 17 * clo + b;
        T[(4 * l4 + 0) * 272 + jp] = v.x;
        T[(4 * l4 + 1) * 272 + jp] = v.y;
        T[(4 * l4 + 2) * 272 + jp] = v.z;
        T[(4 * l4 + 3) * 272 + jp] = v.w;
    }
    __syncthreads();
#pragma unroll
    for (int it = 0; it < 4; ++it) {
        int p  = tid + it * 256;    // 0..1023
        int ll = p >> 6;            // 0..15
        int c4 = p & 63;            // float4 column
        int j0 = 4 * c4;
        int base = ll * 272 + 17 * (j0 >> 4) + (j0 & 15);  // j0..j0+3 share c_lo
        float4 v;
        v.x = T[base + 0];
        v.y = T[base + 1];
        v.z = T[base + 2];
        v.w = T[base + 3];
        int n = (l0 + ll) * 16 + m;
        *(float4*)(A + (size_t)n * DD + j0) = v;
    }
}

// ---------------- kernel 2: distances + argmin + quantize + loss ----------------
// 64 rows/block, K-tile 128, d-chunk 64. Thread tile 8 rows x 4 ks (acc 32 VGPR).
// rg = tid&7 (8 row groups, rows rg+8i), kg = tid>>3 (32 k groups, ks kg+32j).
// score = ||e||^2 - 2*dot ; ||x||^2 dropped (argmin-invariant).
__global__ __launch_bounds__(256, 2) void vq_main(const float* __restrict__ emb,
                                                  const float* __restrict__ enorm,
                                                  float* out) {
    const int RB = 64, KT = 128, DC = 64, SA = 68, SE = 68;
    __shared__ float smem[64 * 68 + 128 * 68];  // sA (17.4KB) + sE (34.8KB)
    __shared__ int   sIdx[64];
    __shared__ float wsum[4];
    float* sA  = smem;
    float* sEb = smem + 64 * 68;
    float* redv = sEb;                 // reuse sE region after k-loop
    int*   redi = (int*)(sEb + 64 * 32);

    int tid = threadIdx.x;
    int n0  = blockIdx.x * RB;
    int rg  = tid & 7;
    int kg  = tid >> 3;

    float minv[8];
    int   mini[8];
#pragma unroll
    for (int i = 0; i < 8; ++i) { minv[i] = 3.4e38f; mini[i] = 0; }

    const float* A = out;  // flat rows, written by vq_transpose (same layout as Q out)

    for (int kt = 0; kt < KC / KT; ++kt) {
        int k0 = kt * KT;
        float acc[8][4];
#pragma unroll
        for (int i = 0; i < 8; ++i)
#pragma unroll
            for (int j = 0; j < 4; ++j) acc[i][j] = 0.f;

        for (int dc = 0; dc < DD / DC; ++dc) {
            int d0 = dc * DC;
            __syncthreads();
            // stage A chunk: 64 rows x 64 d
#pragma unroll
            for (int it = 0; it < 4; ++it) {
                int p  = tid + it * 256;
                int r  = p >> 4;
                int c4 = p & 15;
                float4 v = *(const float4*)(A + (size_t)(n0 + r) * DD + d0 + 4 * c4);
                *(float4*)(sA + r * SA + 4 * c4) = v;
            }
            // stage E chunk: 128 ks x 64 d
#pragma unroll
            for (int it = 0; it < 8; ++it) {
                int p  = tid + it * 256;
                int r  = p >> 4;
                int c4 = p & 15;
                float4 v = *(const float4*)(emb + (size_t)(k0 + r) * DD + d0 + 4 * c4);
                *(float4*)(sEb + r * SE + 4 * c4) = v;
            }
            __syncthreads();
#pragma unroll
            for (int d4 = 0; d4 < DC / 4; ++d4) {
                float4 av[8], ev[4];
#pragma unroll
                for (int i = 0; i < 8; ++i)
                    av[i] = *(const float4*)(sA + (rg + 8 * i) * SA + 4 * d4);
#pragma unroll
                for (int j = 0; j < 4; ++j)
                    ev[j] = *(const float4*)(sEb + (kg + 32 * j) * SE + 4 * d4);
#pragma unroll
                for (int i = 0; i < 8; ++i)
#pragma unroll
                    for (int j = 0; j < 4; ++j)
                        acc[i][j] += av[i].x * ev[j].x + av[i].y * ev[j].y +
                                     av[i].z * ev[j].z + av[i].w * ev[j].w;
            }
        }
        // fold this k-tile into the running argmin (k ascending per thread -> '<' keeps first)
#pragma unroll
        for (int j = 0; j < 4; ++j) {
            int k = k0 + kg + 32 * j;
            float en = enorm[k];
#pragma unroll
            for (int i = 0; i < 8; ++i) {
                float s = en - 2.f * acc[i][j];
                if (s < minv[i]) { minv[i] = s; mini[i] = k; }
            }
        }
    }

    __syncthreads();  // all sE reads done; safe to reuse as reduction scratch
#pragma unroll
    for (int i = 0; i < 8; ++i) {
        int r = rg + 8 * i;
        redv[r * 32 + kg] = minv[i];
        redi[r * 32 + kg] = mini[i];
    }
    __syncthreads();
    if (tid < 64) {
        int r = tid;
        float bv = redv[r * 32];
        int   bi = redi[r * 32];
        for (int t = 1; t < 32; ++t) {
            float v  = redv[r * 32 + t];
            int   ii = redi[r * 32 + t];
            if (v < bv || (v == bv && ii < bi)) { bv = v; bi = ii; }
        }
        sIdx[r] = bi;
        out[IDX_OFF + n0 + r] = (float)bi;  // harness reads flat buffer as f32
    }
    __syncthreads();

    // quantize (overwrite own A rows after reading them) + loss partial
    float lacc = 0.f;
#pragma unroll
    for (int it = 0; it < 16; ++it) {
        int p  = tid + it * 256;   // 0..4095
        int r  = p >> 6;           // row 0..63 (whole wave shares a row)
        int c4 = p & 63;
        int k  = sIdx[r];
        size_t off = (size_t)(n0 + r) * DD + 4 * c4;
        float4 q = *(const float4*)(emb + (size_t)k * DD + 4 * c4);
        float4 a = *(const float4*)(out + off);   // read-before-write, same thread
        float dx = q.x - a.x, dy = q.y - a.y, dz = q.z - a.z, dw = q.w - a.w;
        lacc += dx * dx + dy * dy + dz * dz + dw * dw;
        *(float4*)(out + off) = q;
    }
#pragma unroll
    for (int off = 32; off > 0; off >>= 1) lacc += __shfl_down(lacc, off, 64);
    if ((tid & 63) == 0) wsum[tid >> 6] = lacc;
    __syncthreads();
    if (tid == 0) {
        float bs = wsum[0] + wsum[1] + wsum[2] + wsum[3];
        atomicAdd(out + LOSS_OFF, bs * (1.25f / 8388608.0f));
    }
}

extern "C" void kernel_launch(void* const* d_in, const int* in_sizes, int n_in,
                              void* d_out, int out_size, void* d_ws, size_t ws_size,
                              hipStream_t stream) {
    (void)in_sizes; (void)n_in; (void)out_size; (void)ws_size;
    const float* ze  = (const float*)d_in[0];
    const float* emb = (const float*)d_in[1];
    float* out   = (float*)d_out;
    float* enorm = (float*)d_ws;   // 8 KB scratch

    // loss accumulator slot must start at 0 (d_ws/d_out are poisoned 0xAA)
    hipMemsetAsync((char*)d_out + (size_t)LOSS_OFF * 4, 0, 4, stream);
    vq_enorm<<<KC / 256, 256, 0, stream>>>(emb, enorm);
    vq_transpose<<<2048, 256, 0, stream>>>(ze, out);
    vq_main<<<NROWS / 64, 256, 0, stream>>>(emb, enorm, out);
}

// Round 2
// 1614.794 us; speedup vs baseline: 4.2549x; 4.2549x over previous
//
#include <hip/hip_runtime.h>

// Problem: B=16, C=256, L=2048, K=2048 codewords, D=256 codebook dim.
// flat[n][j] = z_e[b=j&15][c=(n&15)*16+(j>>4)][l=n>>4],  N=32768 rows.
// Outputs (f32, concatenated): quantized[8388608], indices[32768], loss[1].
// vq_loss = 1.25 * mean((quantized - flat)^2)   (stop_gradient is value-neutral)

#define ZE_CL   (256 * 2048)
#define NROWS   32768
#define KC      2048
#define DD      256
#define IDX_OFF 8388608
#define LOSS_OFF (8388608 + 32768)

// ---------------- kernel 0: codeword squared norms -> ws ----------------
__global__ void vq_enorm(const float* __restrict__ emb, float* __restrict__ enorm) {
    int k = blockIdx.x * blockDim.x + threadIdx.x;
    if (k >= KC) return;
    const float4* e4 = (const float4*)(emb + (size_t)k * DD);
    float s = 0.f;
#pragma unroll
    for (int i = 0; i < DD / 4; ++i) {
        float4 v = e4[i];
        s += v.x * v.x + v.y * v.y + v.z * v.z + v.w * v.w;
    }
    enorm[k] = s;
}

// ---------------- kernel 1: z_e -> flat A (materialized in d_out Q region) ----
__global__ void vq_transpose(const float* __restrict__ ze, float* __restrict__ A) {
    __shared__ float T[16 * 272];
    int tid = threadIdx.x;
    int m  = blockIdx.x & 15;
    int lt = blockIdx.x >> 4;       // 0..127
    int l0 = lt * 16;
#pragma unroll
    for (int it = 0; it < 4; ++it) {
        int p   = tid + it * 256;   // 0..1023
        int b   = p >> 6;           // 0..15
        int clo = (p >> 2) & 15;    // 0..15
        int l4  = p & 3;            // 0..3
        const float* g = ze + (size_t)b * ZE_CL + (size_t)(m * 16 + clo) * 2048 + l0 + 4 * l4;
        float4 v = *(const float4*)g;
        int jp = 17 * clo + b;
        T[(4 * l4 + 0) * 272 + jp] = v.x;
        T[(4 * l4 + 1) * 272 + jp] = v.y;
        T[(4 * l4 + 2) * 272 + jp] = v.z;
        T[(4 * l4 + 3) * 272 + jp] = v.w;
    }
    __syncthreads();
#pragma unroll
    for (int it = 0; it < 4; ++it) {
        int p  = tid + it * 256;    // 0..1023
        int ll = p >> 6;            // 0..15
        int c4 = p & 63;            // float4 column
        int j0 = 4 * c4;
        int base = ll * 272 + 17 * (j0 >> 4) + (j0 & 15);
        float4 v;
        v.x = T[base + 0];
        v.y = T[base + 1];
        v.z = T[base + 2];
        v.w = T[base + 3];
        int n = (l0 + ll) * 16 + m;
        *(float4*)(A + (size_t)n * DD + j0) = v;
    }
}

// ---------------- kernel 2: distances + argmin + quantize + loss ----------------
// 64 rows/block, K-tile 64, d-chunk 64. Thread tile 4 rows x 4 ks (acc 16 VGPR,
// total live ~85 < 128 cap -> no spill). rg = tid&15 (rows rg+16i),
// kg = tid>>4 (ks kg+16j). score = ||e||^2 - 2*dot (||x||^2 argmin-invariant).
__global__ __launch_bounds__(256, 2) void vq_main(const float* __restrict__ emb,
                                                  const float* __restrict__ enorm,
                                                  float* out) {
    const int RB = 64, KT = 64, DC = 64, SA = 68, SE = 68;
    __shared__ float smem[64 * 68 + 64 * 68];  // sA 17.4KB + sE 17.4KB
    __shared__ int   sIdx[64];
    __shared__ float wsum[4];
    float* sA  = smem;
    float* sEb = smem + 64 * SA;
    float* redv = sEb;                 // reuse sE region after k-loop
    int*   redi = (int*)(sEb + 64 * 16);

    int tid = threadIdx.x;
    int n0  = blockIdx.x * RB;
    int rg  = tid & 15;
    int kg  = tid >> 4;

    float minv[4];
    int   mini[4];
#pragma unroll
    for (int i = 0; i < 4; ++i) { minv[i] = 3.4e38f; mini[i] = 0; }

    const float* A = out;  // flat rows, written by vq_transpose

    for (int kt = 0; kt < KC / KT; ++kt) {
        int k0 = kt * KT;
        float acc[4][4];
#pragma unroll
        for (int i = 0; i < 4; ++i)
#pragma unroll
            for (int j = 0; j < 4; ++j) acc[i][j] = 0.f;

        for (int dc = 0; dc < DD / DC; ++dc) {
            int d0 = dc * DC;
            __syncthreads();
            // stage A chunk: 64 rows x 64 d (1024 float4)
#pragma unroll
            for (int it = 0; it < 4; ++it) {
                int p  = tid + it * 256;
                int r  = p >> 4;
                int c4 = p & 15;
                float4 v = *(const float4*)(A + (size_t)(n0 + r) * DD + d0 + 4 * c4);
                *(float4*)(sA + r * SA + 4 * c4) = v;
            }
            // stage E chunk: 64 ks x 64 d (1024 float4)
#pragma unroll
            for (int it = 0; it < 4; ++it) {
                int p  = tid + it * 256;
                int r  = p >> 4;
                int c4 = p & 15;
                float4 v = *(const float4*)(emb + (size_t)(k0 + r) * DD + d0 + 4 * c4);
                *(float4*)(sEb + r * SE + 4 * c4) = v;
            }
            __syncthreads();
#pragma unroll
            for (int d4 = 0; d4 < DC / 4; ++d4) {
                float4 av[4], ev[4];
#pragma unroll
                for (int i = 0; i < 4; ++i)
                    av[i] = *(const float4*)(sA + (rg + 16 * i) * SA + 4 * d4);
#pragma unroll
                for (int j = 0; j < 4; ++j)
                    ev[j] = *(const float4*)(sEb + (kg + 16 * j) * SE + 4 * d4);
#pragma unroll
                for (int i = 0; i < 4; ++i)
#pragma unroll
                    for (int j = 0; j < 4; ++j)
                        acc[i][j] += av[i].x * ev[j].x + av[i].y * ev[j].y +
                                     av[i].z * ev[j].z + av[i].w * ev[j].w;
            }
        }
        // fold k-tile into running argmin (k ascending per thread -> '<' keeps first)
#pragma unroll
        for (int j = 0; j < 4; ++j) {
            int k = k0 + kg + 16 * j;
            float en = enorm[k];
#pragma unroll
            for (int i = 0; i < 4; ++i) {
                float s = en - 2.f * acc[i][j];
                if (s < minv[i]) { minv[i] = s; mini[i] = k; }
            }
        }
    }

    __syncthreads();  // all sE reads done; reuse as reduction scratch
#pragma unroll
    for (int i = 0; i < 4; ++i) {
        int r = rg + 16 * i;
        redv[r * 16 + kg] = minv[i];
        redi[r * 16 + kg] = mini[i];
    }
    __syncthreads();
    if (tid < 64) {
        int r = tid;
        float bv = redv[r * 16];
        int   bi = redi[r * 16];
        for (int t = 1; t < 16; ++t) {
            float v  = redv[r * 16 + t];
            int   ii = redi[r * 16 + t];
            if (v < bv || (v == bv && ii < bi)) { bv = v; bi = ii; }
        }
        sIdx[r] = bi;
        out[IDX_OFF + n0 + r] = (float)bi;  // harness reads flat buffer as f32
    }
    __syncthreads();

    // quantize (overwrite own A rows after reading them) + loss partial
    float lacc = 0.f;
#pragma unroll
    for (int it = 0; it < 16; ++it) {
        int p  = tid + it * 256;   // 0..4095
        int r  = p >> 6;           // row 0..63 (whole wave shares a row)
        int c4 = p & 63;
        int k  = sIdx[r];
        size_t off = (size_t)(n0 + r) * DD + 4 * c4;
        float4 q = *(const float4*)(emb + (size_t)k * DD + 4 * c4);
        float4 a = *(const float4*)(out + off);   // read-before-write, same thread
        float dx = q.x - a.x, dy = q.y - a.y, dz = q.z - a.z, dw = q.w - a.w;
        lacc += dx * dx + dy * dy + dz * dz + dw * dw;
        *(float4*)(out + off) = q;
    }
#pragma unroll
    for (int off = 32; off > 0; off >>= 1) lacc += __shfl_down(lacc, off, 64);
    if ((tid & 63) == 0) wsum[tid >> 6] = lacc;
    __syncthreads();
    if (tid == 0) {
        float bs = wsum[0] + wsum[1] + wsum[2] + wsum[3];
        atomicAdd(out + LOSS_OFF, bs * (1.25f / 8388608.0f));
    }
}

extern "C" void kernel_launch(void* const* d_in, const int* in_sizes, int n_in,
                              void* d_out, int out_size, void* d_ws, size_t ws_size,
                              hipStream_t stream) {
    (void)in_sizes; (void)n_in; (void)out_size; (void)ws_size;
    const float* ze  = (const float*)d_in[0];
    const float* emb = (const float*)d_in[1];
    float* out   = (float*)d_out;
    float* enorm = (float*)d_ws;   // 8 KB scratch

    hipMemsetAsync((char*)d_out + (size_t)LOSS_OFF * 4, 0, 4, stream);
    vq_enorm<<<KC / 256, 256, 0, stream>>>(emb, enorm);
    vq_transpose<<<2048, 256, 0, stream>>>(ze, out);
    vq_main<<<NROWS / 64, 256, 0, stream>>>(emb, enorm, out);
}